// Round 1
// baseline (89.358 us; speedup 1.0000x reference)
//
#include <hip/hip_runtime.h>

// LinearAttention: B=1, H=16, N=2048, D=DV=64, causal=1, f32 in/out.
// Three dispatches (measured-best structure, R5):
//  k1: per-chunk S_c^T = (Kf^T V)^T in bf16, z_c = colsum(Kf) f32,
//      plus bf16 row-major Kf / V handoff buffers for k2.
//  kp: batched exclusive prefix scan over chunk axis (in-place, bf16).
//  k2: W = mask(Qf Kf^T), O = W V + Qf S_pre, den fused as extra column.
// Measured bracketing (R2-R8): any fusion of these via grid.sync (225us),
// device-fence election (161us), or per-consumer redundant prefix (92-95us)
// regresses vs the 3-dispatch form (88.9us). Do not re-fuse.
// R9 theory: top-5 rocprof dispatches are all 256MiB ws-poison fills
// (~44.5us @75% HBM peak) -> dur_us is fill + latency-bound kernel tail.
// R9 changes: kp = single latency round (full 32-chunk reg prefetch,
// 4-elem slices, 64-thr blocks); k2 reads bf16 Kf/V (no fmap-exp on K);
// k2 second __syncthreads removed (sW rows are wave-private).
#define Hh   16
#define Nn   2048
#define Dd   64
#define DVv  64
#define Ll   64
#define Cc   (Nn / Ll)      // 32
#define HCc  (Hh * Cc)      // 512
#define EPSf 1e-6f
#define LDP  72             // bf16 row stride (+8 pad, keeps 16B align)

typedef __attribute__((ext_vector_type(8))) __bf16 bf16x8;
typedef __attribute__((ext_vector_type(4))) __bf16 bf16x4;
typedef __attribute__((ext_vector_type(4))) float  f32x4;

__device__ __forceinline__ float fmap(float x) {
    return x > 0.0f ? (x + 1.0f) : __expf(x);   // elu(x)+1
}
__device__ __forceinline__ __bf16 tobf(float x) { return (__bf16)x; }

// ---------------- k1: S_c^T (bf16) + z_c (f32) + bf16 Kf/V handoff --------
__global__ __launch_bounds__(256) void k_chunk_sums(
    const float* __restrict__ Kg, const float* __restrict__ Vg,
    __bf16* __restrict__ SwsT, float* __restrict__ zws,
    __bf16* __restrict__ Kfg, __bf16* __restrict__ Vbg)
{
    __shared__ __align__(16) __bf16 sKT[Dd][LDP];   // Kf^T: [d][m]
    __shared__ __align__(16) __bf16 sVT[80][LDP];   // V^T: [e][m]; row 64 = ones
    const int t  = threadIdx.x;
    const int hc = blockIdx.x;
    const float4* K4 = (const float4*)(Kg + (size_t)hc * (Ll * Dd));
    const float4* V4 = (const float4*)(Vg + (size_t)hc * (Ll * DVv));
    __bf16* Kfo = Kfg + (size_t)hc * (Ll * Dd);
    __bf16* Vbo = Vbg + (size_t)hc * (Ll * DVv);
    for (int i = t; i < (Ll * Dd) / 4; i += 256) {   // 4 iters
        float4 k4 = K4[i];
        float4 v4 = V4[i];
        const int m  = i >> 4;
        const int c0 = (i & 15) * 4;
        bf16x4 kv = { tobf(fmap(k4.x)), tobf(fmap(k4.y)), tobf(fmap(k4.z)), tobf(fmap(k4.w)) };
        bf16x4 vv = { tobf(v4.x), tobf(v4.y), tobf(v4.z), tobf(v4.w) };
        *(bf16x4*)&Kfo[m * Dd + c0]  = kv;           // bf16 handoff for k2
        *(bf16x4*)&Vbo[m * DVv + c0] = vv;
        sKT[c0 + 0][m] = kv[0];
        sKT[c0 + 1][m] = kv[1];
        sKT[c0 + 2][m] = kv[2];
        sKT[c0 + 3][m] = kv[3];
        sVT[c0 + 0][m] = vv[0];
        sVT[c0 + 1][m] = vv[1];
        sVT[c0 + 2][m] = vv[2];
        sVT[c0 + 3][m] = vv[3];
    }
    for (int i = t; i < 16 * LDP; i += 256) {        // aux rows 64..79
        const int r = i / LDP, c = i % LDP;
        sVT[64 + r][c] = (r == 0) ? (__bf16)1.0f : (__bf16)0.0f;
    }
    __syncthreads();

    const int lane = t & 63, wv = t >> 6;
    const int col = lane & 15, quad = lane >> 4;
    __bf16* So = SwsT + (size_t)hc * (Dd * DVv);     // S^T layout: [e][d]
    for (int et = 0; et < 5; ++et) {
        f32x4 acc = {0.f, 0.f, 0.f, 0.f};
#pragma unroll
        for (int ks = 0; ks < 2; ++ks) {
            bf16x8 a = *(const bf16x8*)&sKT[wv * 16 + col][ks * 32 + quad * 8];
            bf16x8 b = *(const bf16x8*)&sVT[et * 16 + col][ks * 32 + quad * 8];
            acc = __builtin_amdgcn_mfma_f32_16x16x32_bf16(a, b, acc, 0, 0, 0);
        }
        if (et < 4) {
            const int e = et * 16 + col;
            const int d = wv * 16 + quad * 4;
            bf16x4 s4 = { tobf(acc[0]), tobf(acc[1]), tobf(acc[2]), tobf(acc[3]) };
            *(bf16x4*)&So[e * Dd + d] = s4;
        } else if (col == 0) {
#pragma unroll
            for (int j = 0; j < 4; ++j)
                zws[hc * Dd + wv * 16 + quad * 4 + j] = acc[j];
        }
    }
}

// ---------------- kp: exclusive prefix over chunk axis -------------------
// Single latency round: all 32 chunk values prefetched into registers,
// then serial carry + stores. 4-elem slices: blocks 0..255 cover 16384
// slices (64 thr each); blocks 256..271 do the z scans (f32).
__global__ __launch_bounds__(64) void k_prefix(
    __bf16* __restrict__ SwsT, float* __restrict__ zws)
{
    const int b = blockIdx.x, t = threadIdx.x;
    if (b < 256) {
        const int gid = b * 64 + t;               // [0, 16384)
        const int h   = gid >> 10;                // 1024 slices per head
        const int sl  = gid & 1023;
        __bf16* base = SwsT + ((size_t)h * Cc) * (Dd * DVv) + sl * 4;
        bf16x4 v[Cc];
#pragma unroll
        for (int k = 0; k < Cc; ++k)              // 32 loads, all in flight
            v[k] = *(const bf16x4*)(base + (size_t)k * (Dd * DVv));
        float r0 = 0.f, r1 = 0.f, r2 = 0.f, r3 = 0.f;
#pragma unroll
        for (int k = 0; k < Cc; ++k) {
            bf16x4 o = { tobf(r0), tobf(r1), tobf(r2), tobf(r3) };
            *(bf16x4*)(base + (size_t)k * (Dd * DVv)) = o;
            r0 += (float)v[k][0];
            r1 += (float)v[k][1];
            r2 += (float)v[k][2];
            r3 += (float)v[k][3];
        }
    } else {
        const int gid = (b - 256) * 64 + t;       // [0, 1024)
        const int h = gid >> 6, d = gid & 63;
        float* zb = zws + (size_t)(h * Cc) * Dd + d;
        float v[Cc];
#pragma unroll
        for (int k = 0; k < Cc; ++k) v[k] = zb[(size_t)k * Dd];
        float run = 0.f;
#pragma unroll
        for (int k = 0; k < Cc; ++k) {
            zb[(size_t)k * Dd] = run;
            run += v[k];
        }
    }
}

// ---------------- k2: W-GEMM + O-GEMM, bf16 Kf/V + S_pre staged ----------
__global__ __launch_bounds__(256) void k_output(
    const float* __restrict__ Qg, const __bf16* __restrict__ Kfg,
    const __bf16* __restrict__ Vbg, const __bf16* __restrict__ SwsT,
    const float* __restrict__ zws, float* __restrict__ Og)
{
    __shared__ __align__(16) __bf16 aQ[Ll][LDP];    // Qf rows (A)
    __shared__ __align__(16) __bf16 aK[Ll][LDP];    // Kf rows (B^T for W-GEMM)
    __shared__ __align__(16) __bf16 sW[Ll][LDP];    // masked W (A for O-GEMM)
    __shared__ __align__(16) __bf16 bV[80][LDP];    // V^T; row 64 = ones
    __shared__ __align__(16) __bf16 bS[80][LDP];    // Spre^T; row 64 = z_pre
    const int t  = threadIdx.x;
    const int hc = blockIdx.x;
    const int lane = t & 63, wv = t >> 6;
    const int col = lane & 15, quad = lane >> 4;

    // Stage Qf (f32 + fmap) / Kf (bf16 copy) / V^T (bf16 transpose)
    {
        const float4* Q4 = (const float4*)(Qg + (size_t)hc * (Ll * Dd));
        for (int i = t; i < (Ll * Dd) / 4; i += 256) {   // 4 iters
            float4 q4 = Q4[i];
            const int m  = i >> 4;
            const int c0 = (i & 15) * 4;
            bf16x4 qv = { tobf(fmap(q4.x)), tobf(fmap(q4.y)), tobf(fmap(q4.z)), tobf(fmap(q4.w)) };
            *(bf16x4*)&aQ[m][c0] = qv;
        }
        const __bf16* Kf = Kfg + (size_t)hc * (Ll * Dd);
        const __bf16* Vb = Vbg + (size_t)hc * (Ll * DVv);
        for (int i = t; i < (Ll * Dd) / 8; i += 256) {   // 2 iters
            bf16x8 k8 = *(const bf16x8*)(Kf + i * 8);
            bf16x8 v8 = *(const bf16x8*)(Vb + i * 8);
            const int m  = i >> 3;
            const int c0 = (i & 7) * 8;
            *(bf16x8*)&aK[m][c0] = k8;                   // straight copy
#pragma unroll
            for (int j = 0; j < 8; ++j) bV[c0 + j][m] = v8[j];
        }
        for (int i = t; i < 16 * LDP; i += 256) {
            const int r = i / LDP, cc = i % LDP;
            bV[64 + r][cc] = (r == 0) ? (__bf16)1.0f : (__bf16)0.0f;
        }
    }

    // Stage S_pre^T (bf16, vectorized) + z_pre row
    {
        const __bf16* Sp = SwsT + (size_t)hc * (Dd * DVv);
        for (int i = t; i < (Dd * DVv) / 8; i += 256) {   // 2 iters
            bf16x8 s = *(const bf16x8*)(Sp + i * 8);
            const int e = i >> 3, d0 = (i & 7) * 8;
            *(bf16x8*)&bS[e][d0] = s;
        }
        if (t < Dd) bS[64][t] = tobf(zws[hc * Dd + t]);
        for (int i = t; i < 16 * LDP; i += 256) {
            const int r = i / LDP, cc = i % LDP;
            if (!(r == 0 && cc < Dd)) bS[64 + r][cc] = (__bf16)0.0f;
        }
    }
    __syncthreads();

    // W-GEMM: W = mask(Qf Kf^T)
#pragma unroll 1
    for (int mt = 0; mt < 4; ++mt) {
        f32x4 wacc = {0.f, 0.f, 0.f, 0.f};
#pragma unroll
        for (int ks = 0; ks < 2; ++ks) {
            bf16x8 a = *(const bf16x8*)&aQ[wv * 16 + col][ks * 32 + quad * 8];
            bf16x8 b = *(const bf16x8*)&aK[mt * 16 + col][ks * 32 + quad * 8];
            wacc = __builtin_amdgcn_mfma_f32_16x16x32_bf16(a, b, wacc, 0, 0, 0);
        }
#pragma unroll
        for (int j = 0; j < 4; ++j) {
            const int n = wv * 16 + quad * 4 + j;
            const int m = mt * 16 + col;
            sW[n][m] = tobf(m <= n ? wacc[j] : 0.0f);
        }
    }
    // NO second __syncthreads: wave wv reads only sW rows [wv*16, wv*16+16),
    // which it alone wrote; same-wave LDS RAW is ordered by lgkmcnt.

    // O-GEMM: acc[et] = W.(V^T block) + Qf.(Spre^T block); et=4 -> den
    f32x4 accs[5];
#pragma unroll 1
    for (int et = 0; et < 5; ++et) {
        f32x4 acc = {0.f, 0.f, 0.f, 0.f};
#pragma unroll
        for (int ks = 0; ks < 2; ++ks) {
            bf16x8 a = *(const bf16x8*)&sW[wv * 16 + col][ks * 32 + quad * 8];
            bf16x8 b = *(const bf16x8*)&bV[et * 16 + col][ks * 32 + quad * 8];
            acc = __builtin_amdgcn_mfma_f32_16x16x32_bf16(a, b, acc, 0, 0, 0);
        }
#pragma unroll
        for (int ks = 0; ks < 2; ++ks) {
            bf16x8 a = *(const bf16x8*)&aQ[wv * 16 + col][ks * 32 + quad * 8];
            bf16x8 b = *(const bf16x8*)&bS[et * 16 + col][ks * 32 + quad * 8];
            acc = __builtin_amdgcn_mfma_f32_16x16x32_bf16(a, b, acc, 0, 0, 0);
        }
        accs[et] = acc;
    }
    float dn[4];
#pragma unroll
    for (int j = 0; j < 4; ++j) dn[j] = __shfl(accs[4][j], lane & 48);

    float* Oc = Og + (size_t)hc * (Ll * DVv);
#pragma unroll
    for (int et = 0; et < 4; ++et) {
#pragma unroll
        for (int j = 0; j < 4; ++j) {
            const int n = wv * 16 + quad * 4 + j;
            Oc[n * DVv + et * 16 + col] = accs[et][j] / (dn[j] + EPSf);
        }
    }
}

extern "C" void kernel_launch(void* const* d_in, const int* in_sizes, int n_in,
                              void* d_out, int out_size, void* d_ws, size_t ws_size,
                              hipStream_t stream) {
    const float* Q = (const float*)d_in[0];
    const float* K = (const float*)d_in[1];
    const float* V = (const float*)d_in[2];
    char* ws = (char*)d_ws;
    const size_t szS = (size_t)HCc * Dd * DVv * sizeof(__bf16);   // 4 MiB
    const size_t szZ = (size_t)HCc * Dd * sizeof(float);          // 128 KiB
    __bf16* SwsT = (__bf16*)ws;
    float*  zws  = (float*)(ws + szS);
    __bf16* Kfws = (__bf16*)(ws + szS + szZ);                     // 4 MiB
    __bf16* Vbws = Kfws + (size_t)HCc * Ll * Dd;                  // 4 MiB
    float* out = (float*)d_out;

    k_chunk_sums<<<HCc, 256, 0, stream>>>(K, V, SwsT, zws, Kfws, Vbws);
    k_prefix<<<272, 64, 0, stream>>>(SwsT, zws);
    k_output<<<HCc, 256, 0, stream>>>(Q, Kfws, Vbws, SwsT, zws, out);
}